// Round 11
// baseline (1384.122 us; speedup 1.0000x reference)
//
#include <hip/hip_runtime.h>
#include <hip/hip_bf16.h>

#define NN 100000      // nodes
#define NE 1600000     // edges
#define HD 128         // hidden dim
#define NG 64          // graphs
#define NC 10          // classes
#define NB 391         // dst buckets: b = dst >> 8 (256 nodes per bucket)
#define BCAP 4608      // per-bucket capacity (mean 4096, sigma 64 -> +8 sigma)
#define CHUNK 6400     // edges per k_bin2 block (NE/CHUNK = 250 exactly)

typedef short bf16x8 __attribute__((ext_vector_type(8)));
typedef float f32x4 __attribute__((ext_vector_type(4)));

__device__ __forceinline__ unsigned pk_bf16(float a, float b) {
  unsigned ua = __float_as_uint(a);
  unsigned ub = __float_as_uint(b);
  unsigned ra = (ua + 0x7fffu + ((ua >> 16) & 1u)) >> 16;  // RNE to bf16
  unsigned rb = (ub + 0x7fffu + ((ub >> 16) & 1u)) >> 16;
  return ra | (rb << 16);
}

__device__ __forceinline__ void acc_u4(float* acc, uint4 v) {
  acc[0] += __uint_as_float(v.x << 16);
  acc[1] += __uint_as_float(v.x & 0xffff0000u);
  acc[2] += __uint_as_float(v.y << 16);
  acc[3] += __uint_as_float(v.y & 0xffff0000u);
  acc[4] += __uint_as_float(v.z << 16);
  acc[5] += __uint_as_float(v.z & 0xffff0000u);
  acc[6] += __uint_as_float(v.w << 16);
  acc[7] += __uint_as_float(v.w & 0xffff0000u);
}

// ---------- pass 1: LDS multi-split binning ----------
__global__ __launch_bounds__(256) void k_bin2(const int* __restrict__ src, const int* __restrict__ dst,
                                              int* __restrict__ bcnt, unsigned* __restrict__ bkt) {
  __shared__ int cl[NB];
  __shared__ int cb[NB];
  int tid = threadIdx.x;
  int base_e = blockIdx.x * CHUNK;
  for (int i = tid; i < NB; i += 256) cl[i] = 0;
  __syncthreads();
  #pragma unroll 5
  for (int j = 0; j < CHUNK / 256; ++j) {
    int d = dst[base_e + j * 256 + tid];
    atomicAdd(&cl[d >> 8], 1);
  }
  __syncthreads();
  for (int i = tid; i < NB; i += 256) {
    cb[i] = atomicAdd(&bcnt[i], cl[i]);
    cl[i] = 0;
  }
  __syncthreads();
  #pragma unroll 5
  for (int j = 0; j < CHUNK / 256; ++j) {
    int e = base_e + j * 256 + tid;
    int s = src[e];
    int d = dst[e];
    int b = d >> 8;
    int p = atomicAdd(&cl[b], 1);
    int idx = cb[b] + p;
    if (idx < BCAP)
      bkt[(size_t)b * BCAP + idx] = (unsigned)s | ((unsigned)(d & 255) << 24);
  }
}

// ---------- pass 2: per-bucket CSR build entirely in LDS ----------
__global__ __launch_bounds__(256) void k_fill2(const unsigned* __restrict__ bkt,
                                               const int* __restrict__ bcnt,
                                               int* __restrict__ rows, int* __restrict__ rowe,
                                               float* __restrict__ dis, int* __restrict__ csr) {
  __shared__ unsigned eds[BCAP];
  __shared__ int sc[256];
  int b = blockIdx.x;
  int tid = threadIdx.x;
  int n = bcnt[b];
  if (n > BCAP) n = BCAP;
  const unsigned* mb = bkt + (size_t)b * BCAP;
  for (int i = tid; i < n; i += 256) eds[i] = mb[i];
  sc[tid] = 0;
  __syncthreads();
  for (int i = tid; i < n; i += 256) atomicAdd(&sc[eds[i] >> 24], 1);
  __syncthreads();
  int deg = sc[tid];
  for (int off = 1; off < 256; off <<= 1) {
    int v = (tid >= off) ? sc[tid - off] : 0;
    __syncthreads();
    sc[tid] += v;
    __syncthreads();
  }
  int excl = sc[tid] - deg;
  int node = b * 256 + tid;
  int cbase = b * BCAP;
  if (node < NN) {
    rows[node] = cbase + excl;
    rowe[node] = cbase + excl + deg;
    dis[node] = rsqrtf((float)(deg + 1));
  }
  __syncthreads();
  sc[tid] = excl;
  __syncthreads();
  for (int i = tid; i < n; i += 256) {
    unsigned v = eds[i];
    int p = atomicAdd(&sc[v >> 24], 1);
    csr[cbase + p] = (int)(v & 0xFFFFFFu);
  }
}

// ---------- W prep: WT[n][k] bf16-pair packed, from W[k][n] f32 ----------
__global__ __launch_bounds__(256) void k_prepW(const float* __restrict__ W1, const float* __restrict__ W2,
                                               unsigned* __restrict__ WT1, unsigned* __restrict__ WT2) {
  int i = blockIdx.x * 256 + threadIdx.x;
  const float* W = (i < 8192) ? W1 : W2;
  unsigned* WT = (i < 8192) ? WT1 : WT2;
  int j = i & 8191;
  int n = j >> 6, kh = j & 63;
  WT[j] = pk_bf16(W[(2 * kh) * HD + n], W[(2 * kh + 1) * HD + n]);
}

// ---------- MFMA GEMM: Y[node] = dis[node] * (X @ W), bf16x2-packed out ----------
template<bool BF16IN>
__global__ __launch_bounds__(256) void k_gemm_mfma(const void* __restrict__ Xin,
                                                   const unsigned* __restrict__ WT,
                                                   const float* __restrict__ dis,
                                                   unsigned* __restrict__ Y) {
  __shared__ char WL[128 * 256];  // [n][k] bf16, XOR-swizzled
  __shared__ char XL[64 * 256];   // [node][k] bf16, XOR-swizzled
  int t = threadIdx.x;
  int rowBase = blockIdx.x * 64;
  {
    const uint4* Wg = (const uint4*)WT;
    for (int i = t; i < 2048; i += 256) {
      int n = i >> 4, kq = i & 15;
      uint4 v = Wg[i];
      *(uint4*)(WL + ((n * 256 + kq * 16) ^ ((n & 7) << 4))) = v;
    }
  }
  if (BF16IN) {
    const uint4* Xg = (const uint4*)Xin;
    for (int i = t; i < 1024; i += 256) {
      int node = i >> 4, c = i & 15;
      int gn = rowBase + node; if (gn >= NN) gn = 0;
      uint4 v = Xg[(size_t)gn * 16 + c];
      *(uint4*)(XL + ((node * 256 + c * 16) ^ ((node & 7) << 4))) = v;
    }
  } else {
    const float4* Xg = (const float4*)Xin;
    for (int i = t; i < 1024; i += 256) {
      int node = i >> 4, c = i & 15;
      int gn = rowBase + node; if (gn >= NN) gn = 0;
      float4 a = Xg[(size_t)gn * 32 + c * 2];
      float4 b = Xg[(size_t)gn * 32 + c * 2 + 1];
      uint4 v;
      v.x = pk_bf16(a.x, a.y); v.y = pk_bf16(a.z, a.w);
      v.z = pk_bf16(b.x, b.y); v.w = pk_bf16(b.z, b.w);
      *(uint4*)(XL + ((node * 256 + c * 16) ^ ((node & 7) << 4))) = v;
    }
  }
  __syncthreads();
  int w = t >> 6, l = t & 63;
  int lr = l & 15, lh = l >> 4;
  int xnode = w * 16 + lr;
  bf16x8 bfrag[4];
  #pragma unroll
  for (int ks = 0; ks < 4; ++ks)
    bfrag[ks] = *(bf16x8*)(XL + ((xnode * 256 + (ks * 32 + lh * 8) * 2) ^ ((xnode & 7) << 4)));
  f32x4 acc[8];
  #pragma unroll
  for (int ct = 0; ct < 8; ++ct) acc[ct] = (f32x4){0.f, 0.f, 0.f, 0.f};
  #pragma unroll
  for (int ct = 0; ct < 8; ++ct) {
    int n = ct * 16 + lr;
    #pragma unroll
    for (int ks = 0; ks < 4; ++ks) {
      bf16x8 af = *(bf16x8*)(WL + ((n * 256 + (ks * 32 + lh * 8) * 2) ^ ((n & 7) << 4)));
      acc[ct] = __builtin_amdgcn_mfma_f32_16x16x32_bf16(af, bfrag[ks], acc[ct], 0, 0, 0);
    }
  }
  int gnode = rowBase + w * 16 + lr;
  if (gnode < NN) {
    float ds = dis[gnode];
    uint2* Yp = (uint2*)(Y + (size_t)gnode * 64);
    #pragma unroll
    for (int ct = 0; ct < 8; ++ct) {
      uint2 o;
      o.x = pk_bf16(acc[ct].x * ds, acc[ct].y * ds);
      o.y = pk_bf16(acc[ct].z * ds, acc[ct].w * ds);
      Yp[ct * 4 + lh] = o;
    }
  }
}

// ---------- pull aggregation: one wave per node, uint4-wide gather ----------
// 16 lanes cover a row (lane li owns features [8li,8li+8)); subs (lane>>4) split edges.
// MODE 0: write packed bf16x2 row to OUT; MODE 1: fused mean-pool (atomicAdd into sums)
template<int MODE>
__global__ __launch_bounds__(256) void k_agg(const unsigned* __restrict__ Y, const int* __restrict__ rows,
                                             const int* __restrict__ rowe, const int* __restrict__ csr,
                                             const float* __restrict__ dis,
                                             const float* __restrict__ bias,
                                             unsigned* __restrict__ OUT,
                                             const int* __restrict__ bat, float* __restrict__ sums) {
  int node = __builtin_amdgcn_readfirstlane((blockIdx.x << 2) + (threadIdx.x >> 6));
  int lane = threadIdx.x & 63;
  int sub = lane >> 4, li = lane & 15;
  const uint4* Yv = (const uint4*)Y;   // [node][16] uint4
  float acc[8];
  #pragma unroll
  for (int j = 0; j < 8; ++j) acc[j] = 0.f;
  if (sub == 0) acc_u4(acc, Yv[(size_t)node * 16 + li]);   // self-loop (di*Ys[node])
  int i = rows[node] + sub, end = rowe[node];
  for (; i + 4 < end; i += 8) {
    int s0 = csr[i], s1 = csr[i + 4];
    uint4 v0 = Yv[(size_t)s0 * 16 + li];
    uint4 v1 = Yv[(size_t)s1 * 16 + li];
    acc_u4(acc, v0);
    acc_u4(acc, v1);
  }
  if (i < end) acc_u4(acc, Yv[(size_t)csr[i] * 16 + li]);
  // butterfly reduce across the 4 subs
  #pragma unroll
  for (int j = 0; j < 8; ++j) {
    acc[j] += __shfl_xor(acc[j], 16, 64);
    acc[j] += __shfl_xor(acc[j], 32, 64);
  }
  float di = dis[node];
  const float4* bp = (const float4*)bias;
  float4 b0 = bp[li * 2], b1 = bp[li * 2 + 1];
  float o[8];
  o[0] = fmaxf(fmaf(di, acc[0], b0.x), 0.f);
  o[1] = fmaxf(fmaf(di, acc[1], b0.y), 0.f);
  o[2] = fmaxf(fmaf(di, acc[2], b0.z), 0.f);
  o[3] = fmaxf(fmaf(di, acc[3], b0.w), 0.f);
  o[4] = fmaxf(fmaf(di, acc[4], b1.x), 0.f);
  o[5] = fmaxf(fmaf(di, acc[5], b1.y), 0.f);
  o[6] = fmaxf(fmaf(di, acc[6], b1.z), 0.f);
  o[7] = fmaxf(fmaf(di, acc[7], b1.w), 0.f);
  if (MODE == 0) {
    if (sub == 0) {
      uint4 pv;
      pv.x = pk_bf16(o[0], o[1]);
      pv.y = pk_bf16(o[2], o[3]);
      pv.z = pk_bf16(o[4], o[5]);
      pv.w = pk_bf16(o[6], o[7]);
      ((uint4*)OUT)[(size_t)node * 16 + li] = pv;
    }
  } else {
    if (sub == 0) {
      int g = bat[node];
      float* sp = sums + g * HD + li * 8;
      #pragma unroll
      for (int j = 0; j < 8; ++j) atomicAdd(&sp[j], o[j]);
    }
  }
}

// ---------- graph bounds ----------
__global__ __launch_bounds__(256) void k_bounds(const int* __restrict__ bat, int* __restrict__ sg,
                                                int* __restrict__ eg) {
  int i = blockIdx.x * 256 + threadIdx.x;
  if (i < NN) {
    int g = bat[i];
    if (i == 0 || bat[i - 1] != g) sg[g] = i;
    if (i == NN - 1 || bat[i + 1] != g) eg[g] = i + 1;
  }
}

__global__ __launch_bounds__(640) void k_fc(const float* __restrict__ sums, const int* __restrict__ sg,
                                            const int* __restrict__ eg, const float* __restrict__ Wfc,
                                            const float* __restrict__ bfc, float* __restrict__ out) {
  int t = threadIdx.x;
  if (t >= NG * NC) return;
  int g = t / NC, c = t - g * NC;
  int cntn = eg[g] - sg[g];
  float inv = 1.0f / fmaxf((float)cntn, 1.0f);
  float acc = 0.f;
  for (int f = 0; f < HD; ++f) acc = fmaf(sums[g * HD + f], Wfc[f * NC + c], acc);
  out[t] = acc * inv + bfc[c];
}

extern "C" void kernel_launch(void* const* d_in, const int* in_sizes, int n_in,
                              void* d_out, int out_size, void* d_ws, size_t ws_size,
                              hipStream_t stream) {
  const float* x   = (const float*)d_in[0];
  const int*   ei  = (const int*)d_in[1];
  const int*   bat = (const int*)d_in[2];
  const float* W1  = (const float*)d_in[3];
  const float* b1  = (const float*)d_in[4];
  const float* W2  = (const float*)d_in[5];
  const float* b2  = (const float*)d_in[6];
  const float* Wfc = (const float*)d_in[7];
  const float* bfc = (const float*)d_in[8];
  float* out = (float*)d_out;
  const int* esrc = ei;        // edge_index[0]
  const int* edst = ei + NE;   // edge_index[1]

  char* p = (char*)d_ws;
  auto carve = [&](size_t bytes) { char* r = p; p += (bytes + 255) & ~(size_t)255; return r; };
  float* dis  = (float*)carve((size_t)NN * 4);
  int*   rows = (int*)carve((size_t)NN * 4);
  int*   rowe = (int*)carve((size_t)NN * 4);
  int*   bcnt = (int*)carve((size_t)NB * 4);
  int*   sg   = (int*)carve(NG * 4);
  int*   eg   = (int*)carve(NG * 4);
  float* sums = (float*)carve(NG * HD * 4);
  unsigned* WT1 = (unsigned*)carve(8192 * 4);
  unsigned* WT2 = (unsigned*)carve(8192 * 4);
  int*   csr  = (int*)carve((size_t)NB * BCAP * 4);       // 7.2 MB
  unsigned* Y   = (unsigned*)carve((size_t)NN * 64 * 4);  // 25.6 MB; bkt aliases (dead before gemm1)
  unsigned* H1b = (unsigned*)carve((size_t)NN * 64 * 4);  // 25.6 MB, layer-1 output bf16
  unsigned* bkt = Y;

  hipMemsetAsync(bcnt, 0, (size_t)NB * 4, stream);
  hipMemsetAsync(sums, 0, NG * HD * 4, stream);
  hipMemsetAsync(sg, 0, NG * 4, stream);
  hipMemsetAsync(eg, 0, NG * 4, stream);

  k_bin2<<<NE / CHUNK, 256, 0, stream>>>(esrc, edst, bcnt, bkt);
  k_fill2<<<NB, 256, 0, stream>>>(bkt, bcnt, rows, rowe, dis, csr);
  k_prepW<<<64, 256, 0, stream>>>(W1, W2, WT1, WT2);
  k_bounds<<<(NN + 255) / 256, 256, 0, stream>>>(bat, sg, eg);

  int gblocks = (NN + 63) / 64;
  k_gemm_mfma<false><<<gblocks, 256, 0, stream>>>(x, WT1, dis, Y);
  k_agg<0><<<NN / 4, 256, 0, stream>>>(Y, rows, rowe, csr, dis, b1, H1b, bat, sums);
  k_gemm_mfma<true><<<gblocks, 256, 0, stream>>>(H1b, WT2, dis, Y);
  k_agg<1><<<NN / 4, 256, 0, stream>>>(Y, rows, rowe, csr, dis, b2, nullptr, bat, sums);

  k_fc<<<1, 640, 0, stream>>>(sums, sg, eg, Wfc, bfc, out);
}

// Round 12
// 1383.494 us; speedup vs baseline: 1.0005x; 1.0005x over previous
//
#include <hip/hip_runtime.h>
#include <hip/hip_bf16.h>

#define NN 100000      // nodes
#define NE 1600000     // edges
#define HD 128         // hidden dim
#define NG 64          // graphs
#define NC 10          // classes
#define NB 391         // dst buckets: b = dst >> 8 (256 nodes per bucket)
#define BCAP 4608      // per-bucket capacity (mean 4096, sigma 64 -> +8 sigma)
#define CHUNK 6400     // edges per k_bin2 block (NE/CHUNK = 250 exactly)

typedef short bf16x8 __attribute__((ext_vector_type(8)));
typedef float f32x4 __attribute__((ext_vector_type(4)));

__device__ __forceinline__ unsigned pk_bf16(float a, float b) {
  unsigned ua = __float_as_uint(a);
  unsigned ub = __float_as_uint(b);
  unsigned ra = (ua + 0x7fffu + ((ua >> 16) & 1u)) >> 16;  // RNE to bf16
  unsigned rb = (ub + 0x7fffu + ((ub >> 16) & 1u)) >> 16;
  return ra | (rb << 16);
}

// named-scalar accumulate: keeps everything in VGPRs (rule #20: no arrays via pointers)
#define ACC_U4(v)                                  \
  do {                                             \
    a0 += __uint_as_float((v).x << 16);            \
    a1 += __uint_as_float((v).x & 0xffff0000u);    \
    a2 += __uint_as_float((v).y << 16);            \
    a3 += __uint_as_float((v).y & 0xffff0000u);    \
    a4 += __uint_as_float((v).z << 16);            \
    a5 += __uint_as_float((v).z & 0xffff0000u);    \
    a6 += __uint_as_float((v).w << 16);            \
    a7 += __uint_as_float((v).w & 0xffff0000u);    \
  } while (0)

// ---------- pass 1: LDS multi-split binning ----------
__global__ __launch_bounds__(256) void k_bin2(const int* __restrict__ src, const int* __restrict__ dst,
                                              int* __restrict__ bcnt, unsigned* __restrict__ bkt) {
  __shared__ int cl[NB];
  __shared__ int cb[NB];
  int tid = threadIdx.x;
  int base_e = blockIdx.x * CHUNK;
  for (int i = tid; i < NB; i += 256) cl[i] = 0;
  __syncthreads();
  #pragma unroll 5
  for (int j = 0; j < CHUNK / 256; ++j) {
    int d = dst[base_e + j * 256 + tid];
    atomicAdd(&cl[d >> 8], 1);
  }
  __syncthreads();
  for (int i = tid; i < NB; i += 256) {
    cb[i] = atomicAdd(&bcnt[i], cl[i]);
    cl[i] = 0;
  }
  __syncthreads();
  #pragma unroll 5
  for (int j = 0; j < CHUNK / 256; ++j) {
    int e = base_e + j * 256 + tid;
    int s = src[e];
    int d = dst[e];
    int b = d >> 8;
    int p = atomicAdd(&cl[b], 1);
    int idx = cb[b] + p;
    if (idx < BCAP)
      bkt[(size_t)b * BCAP + idx] = (unsigned)s | ((unsigned)(d & 255) << 24);
  }
}

// ---------- pass 2: per-bucket CSR build entirely in LDS ----------
__global__ __launch_bounds__(256) void k_fill2(const unsigned* __restrict__ bkt,
                                               const int* __restrict__ bcnt,
                                               int* __restrict__ rows, int* __restrict__ rowe,
                                               float* __restrict__ dis, int* __restrict__ csr) {
  __shared__ unsigned eds[BCAP];
  __shared__ int sc[256];
  int b = blockIdx.x;
  int tid = threadIdx.x;
  int n = bcnt[b];
  if (n > BCAP) n = BCAP;
  const unsigned* mb = bkt + (size_t)b * BCAP;
  for (int i = tid; i < n; i += 256) eds[i] = mb[i];
  sc[tid] = 0;
  __syncthreads();
  for (int i = tid; i < n; i += 256) atomicAdd(&sc[eds[i] >> 24], 1);
  __syncthreads();
  int deg = sc[tid];
  for (int off = 1; off < 256; off <<= 1) {
    int v = (tid >= off) ? sc[tid - off] : 0;
    __syncthreads();
    sc[tid] += v;
    __syncthreads();
  }
  int excl = sc[tid] - deg;
  int node = b * 256 + tid;
  int cbase = b * BCAP;
  if (node < NN) {
    rows[node] = cbase + excl;
    rowe[node] = cbase + excl + deg;
    dis[node] = rsqrtf((float)(deg + 1));
  }
  __syncthreads();
  sc[tid] = excl;
  __syncthreads();
  for (int i = tid; i < n; i += 256) {
    unsigned v = eds[i];
    int p = atomicAdd(&sc[v >> 24], 1);
    csr[cbase + p] = (int)(v & 0xFFFFFFu);
  }
}

// ---------- W prep: WT[n][k] bf16-pair packed, from W[k][n] f32 ----------
__global__ __launch_bounds__(256) void k_prepW(const float* __restrict__ W1, const float* __restrict__ W2,
                                               unsigned* __restrict__ WT1, unsigned* __restrict__ WT2) {
  int i = blockIdx.x * 256 + threadIdx.x;
  const float* W = (i < 8192) ? W1 : W2;
  unsigned* WT = (i < 8192) ? WT1 : WT2;
  int j = i & 8191;
  int n = j >> 6, kh = j & 63;
  WT[j] = pk_bf16(W[(2 * kh) * HD + n], W[(2 * kh + 1) * HD + n]);
}

// ---------- MFMA GEMM: Y[node] = dis[node] * (X @ W), bf16x2-packed out ----------
template<bool BF16IN>
__global__ __launch_bounds__(256) void k_gemm_mfma(const void* __restrict__ Xin,
                                                   const unsigned* __restrict__ WT,
                                                   const float* __restrict__ dis,
                                                   unsigned* __restrict__ Y) {
  __shared__ char WL[128 * 256];  // [n][k] bf16, XOR-swizzled
  __shared__ char XL[64 * 256];   // [node][k] bf16, XOR-swizzled
  int t = threadIdx.x;
  int rowBase = blockIdx.x * 64;
  {
    const uint4* Wg = (const uint4*)WT;
    for (int i = t; i < 2048; i += 256) {
      int n = i >> 4, kq = i & 15;
      uint4 v = Wg[i];
      *(uint4*)(WL + ((n * 256 + kq * 16) ^ ((n & 7) << 4))) = v;
    }
  }
  if (BF16IN) {
    const uint4* Xg = (const uint4*)Xin;
    for (int i = t; i < 1024; i += 256) {
      int node = i >> 4, c = i & 15;
      int gn = rowBase + node; if (gn >= NN) gn = 0;
      uint4 v = Xg[(size_t)gn * 16 + c];
      *(uint4*)(XL + ((node * 256 + c * 16) ^ ((node & 7) << 4))) = v;
    }
  } else {
    const float4* Xg = (const float4*)Xin;
    for (int i = t; i < 1024; i += 256) {
      int node = i >> 4, c = i & 15;
      int gn = rowBase + node; if (gn >= NN) gn = 0;
      float4 a = Xg[(size_t)gn * 32 + c * 2];
      float4 b = Xg[(size_t)gn * 32 + c * 2 + 1];
      uint4 v;
      v.x = pk_bf16(a.x, a.y); v.y = pk_bf16(a.z, a.w);
      v.z = pk_bf16(b.x, b.y); v.w = pk_bf16(b.z, b.w);
      *(uint4*)(XL + ((node * 256 + c * 16) ^ ((node & 7) << 4))) = v;
    }
  }
  __syncthreads();
  int w = t >> 6, l = t & 63;
  int lr = l & 15, lh = l >> 4;
  int xnode = w * 16 + lr;
  bf16x8 bfrag[4];
  #pragma unroll
  for (int ks = 0; ks < 4; ++ks)
    bfrag[ks] = *(bf16x8*)(XL + ((xnode * 256 + (ks * 32 + lh * 8) * 2) ^ ((xnode & 7) << 4)));
  f32x4 acc[8];
  #pragma unroll
  for (int ct = 0; ct < 8; ++ct) acc[ct] = (f32x4){0.f, 0.f, 0.f, 0.f};
  #pragma unroll
  for (int ct = 0; ct < 8; ++ct) {
    int n = ct * 16 + lr;
    #pragma unroll
    for (int ks = 0; ks < 4; ++ks) {
      bf16x8 af = *(bf16x8*)(WL + ((n * 256 + (ks * 32 + lh * 8) * 2) ^ ((n & 7) << 4)));
      acc[ct] = __builtin_amdgcn_mfma_f32_16x16x32_bf16(af, bfrag[ks], acc[ct], 0, 0, 0);
    }
  }
  int gnode = rowBase + w * 16 + lr;
  if (gnode < NN) {
    float ds = dis[gnode];
    uint2* Yp = (uint2*)(Y + (size_t)gnode * 64);
    #pragma unroll
    for (int ct = 0; ct < 8; ++ct) {
      uint2 o;
      o.x = pk_bf16(acc[ct].x * ds, acc[ct].y * ds);
      o.y = pk_bf16(acc[ct].z * ds, acc[ct].w * ds);
      Yp[ct * 4 + lh] = o;
    }
  }
}

// ---------- pull aggregation: one wave per node, uint4-wide gather ----------
// 16 lanes cover a row (lane li owns features [8li,8li+8)); subs (lane>>4) split edges.
// MODE 0: write packed bf16x2 row to OUT; MODE 1: fused mean-pool (atomicAdd into sums)
template<int MODE>
__global__ __launch_bounds__(256) void k_agg(const unsigned* __restrict__ Y, const int* __restrict__ rows,
                                             const int* __restrict__ rowe, const int* __restrict__ csr,
                                             const float* __restrict__ dis,
                                             const float* __restrict__ bias,
                                             unsigned* __restrict__ OUT,
                                             const int* __restrict__ bat, float* __restrict__ sums) {
  int node = __builtin_amdgcn_readfirstlane((blockIdx.x << 2) + (threadIdx.x >> 6));
  int lane = threadIdx.x & 63;
  int sub = lane >> 4, li = lane & 15;
  const uint4* Yv = (const uint4*)Y;   // [node][16] uint4
  float a0 = 0.f, a1 = 0.f, a2 = 0.f, a3 = 0.f, a4 = 0.f, a5 = 0.f, a6 = 0.f, a7 = 0.f;
  if (sub == 0) {
    uint4 sv = Yv[(size_t)node * 16 + li];   // self-loop (di*Ys[node])
    ACC_U4(sv);
  }
  int i = rows[node] + sub, end = rowe[node];
  for (; i + 4 < end; i += 8) {
    int s0 = csr[i], s1 = csr[i + 4];
    uint4 v0 = Yv[(size_t)s0 * 16 + li];
    uint4 v1 = Yv[(size_t)s1 * 16 + li];
    ACC_U4(v0);
    ACC_U4(v1);
  }
  if (i < end) {
    uint4 v = Yv[(size_t)csr[i] * 16 + li];
    ACC_U4(v);
  }
  // butterfly reduce across the 4 subs (explicit scalars -> stays in VGPRs)
  a0 += __shfl_xor(a0, 16, 64); a0 += __shfl_xor(a0, 32, 64);
  a1 += __shfl_xor(a1, 16, 64); a1 += __shfl_xor(a1, 32, 64);
  a2 += __shfl_xor(a2, 16, 64); a2 += __shfl_xor(a2, 32, 64);
  a3 += __shfl_xor(a3, 16, 64); a3 += __shfl_xor(a3, 32, 64);
  a4 += __shfl_xor(a4, 16, 64); a4 += __shfl_xor(a4, 32, 64);
  a5 += __shfl_xor(a5, 16, 64); a5 += __shfl_xor(a5, 32, 64);
  a6 += __shfl_xor(a6, 16, 64); a6 += __shfl_xor(a6, 32, 64);
  a7 += __shfl_xor(a7, 16, 64); a7 += __shfl_xor(a7, 32, 64);
  float di = dis[node];
  const float4* bp = (const float4*)bias;
  float4 b0 = bp[li * 2], b1 = bp[li * 2 + 1];
  float o0 = fmaxf(fmaf(di, a0, b0.x), 0.f);
  float o1 = fmaxf(fmaf(di, a1, b0.y), 0.f);
  float o2 = fmaxf(fmaf(di, a2, b0.z), 0.f);
  float o3 = fmaxf(fmaf(di, a3, b0.w), 0.f);
  float o4 = fmaxf(fmaf(di, a4, b1.x), 0.f);
  float o5 = fmaxf(fmaf(di, a5, b1.y), 0.f);
  float o6 = fmaxf(fmaf(di, a6, b1.z), 0.f);
  float o7 = fmaxf(fmaf(di, a7, b1.w), 0.f);
  if (MODE == 0) {
    if (sub == 0) {
      uint4 pv;
      pv.x = pk_bf16(o0, o1);
      pv.y = pk_bf16(o2, o3);
      pv.z = pk_bf16(o4, o5);
      pv.w = pk_bf16(o6, o7);
      ((uint4*)OUT)[(size_t)node * 16 + li] = pv;
    }
  } else {
    if (sub == 0) {
      int g = bat[node];
      float* sp = sums + g * HD + li * 8;
      atomicAdd(&sp[0], o0);
      atomicAdd(&sp[1], o1);
      atomicAdd(&sp[2], o2);
      atomicAdd(&sp[3], o3);
      atomicAdd(&sp[4], o4);
      atomicAdd(&sp[5], o5);
      atomicAdd(&sp[6], o6);
      atomicAdd(&sp[7], o7);
    }
  }
}

// ---------- graph bounds ----------
__global__ __launch_bounds__(256) void k_bounds(const int* __restrict__ bat, int* __restrict__ sg,
                                                int* __restrict__ eg) {
  int i = blockIdx.x * 256 + threadIdx.x;
  if (i < NN) {
    int g = bat[i];
    if (i == 0 || bat[i - 1] != g) sg[g] = i;
    if (i == NN - 1 || bat[i + 1] != g) eg[g] = i + 1;
  }
}

__global__ __launch_bounds__(640) void k_fc(const float* __restrict__ sums, const int* __restrict__ sg,
                                            const int* __restrict__ eg, const float* __restrict__ Wfc,
                                            const float* __restrict__ bfc, float* __restrict__ out) {
  int t = threadIdx.x;
  if (t >= NG * NC) return;
  int g = t / NC, c = t - g * NC;
  int cntn = eg[g] - sg[g];
  float inv = 1.0f / fmaxf((float)cntn, 1.0f);
  float acc = 0.f;
  for (int f = 0; f < HD; ++f) acc = fmaf(sums[g * HD + f], Wfc[f * NC + c], acc);
  out[t] = acc * inv + bfc[c];
}

extern "C" void kernel_launch(void* const* d_in, const int* in_sizes, int n_in,
                              void* d_out, int out_size, void* d_ws, size_t ws_size,
                              hipStream_t stream) {
  const float* x   = (const float*)d_in[0];
  const int*   ei  = (const int*)d_in[1];
  const int*   bat = (const int*)d_in[2];
  const float* W1  = (const float*)d_in[3];
  const float* b1  = (const float*)d_in[4];
  const float* W2  = (const float*)d_in[5];
  const float* b2  = (const float*)d_in[6];
  const float* Wfc = (const float*)d_in[7];
  const float* bfc = (const float*)d_in[8];
  float* out = (float*)d_out;
  const int* esrc = ei;        // edge_index[0]
  const int* edst = ei + NE;   // edge_index[1]

  char* p = (char*)d_ws;
  auto carve = [&](size_t bytes) { char* r = p; p += (bytes + 255) & ~(size_t)255; return r; };
  float* dis  = (float*)carve((size_t)NN * 4);
  int*   rows = (int*)carve((size_t)NN * 4);
  int*   rowe = (int*)carve((size_t)NN * 4);
  int*   bcnt = (int*)carve((size_t)NB * 4);
  int*   sg   = (int*)carve(NG * 4);
  int*   eg   = (int*)carve(NG * 4);
  float* sums = (float*)carve(NG * HD * 4);
  unsigned* WT1 = (unsigned*)carve(8192 * 4);
  unsigned* WT2 = (unsigned*)carve(8192 * 4);
  int*   csr  = (int*)carve((size_t)NB * BCAP * 4);       // 7.2 MB
  unsigned* Y   = (unsigned*)carve((size_t)NN * 64 * 4);  // 25.6 MB; bkt aliases (dead before gemm1)
  unsigned* H1b = (unsigned*)carve((size_t)NN * 64 * 4);  // 25.6 MB, layer-1 output bf16
  unsigned* bkt = Y;

  hipMemsetAsync(bcnt, 0, (size_t)NB * 4, stream);
  hipMemsetAsync(sums, 0, NG * HD * 4, stream);
  hipMemsetAsync(sg, 0, NG * 4, stream);
  hipMemsetAsync(eg, 0, NG * 4, stream);

  k_bin2<<<NE / CHUNK, 256, 0, stream>>>(esrc, edst, bcnt, bkt);
  k_fill2<<<NB, 256, 0, stream>>>(bkt, bcnt, rows, rowe, dis, csr);
  k_prepW<<<64, 256, 0, stream>>>(W1, W2, WT1, WT2);
  k_bounds<<<(NN + 255) / 256, 256, 0, stream>>>(bat, sg, eg);

  int gblocks = (NN + 63) / 64;
  k_gemm_mfma<false><<<gblocks, 256, 0, stream>>>(x, WT1, dis, Y);
  k_agg<0><<<NN / 4, 256, 0, stream>>>(Y, rows, rowe, csr, dis, b1, H1b, bat, sums);
  k_gemm_mfma<true><<<gblocks, 256, 0, stream>>>(H1b, WT2, dis, Y);
  k_agg<1><<<NN / 4, 256, 0, stream>>>(Y, rows, rowe, csr, dis, b2, nullptr, bat, sums);

  k_fc<<<1, 640, 0, stream>>>(sums, sg, eg, Wfc, bfc, out);
}

// Round 13
// 264.584 us; speedup vs baseline: 5.2313x; 5.2289x over previous
//
#include <hip/hip_runtime.h>
#include <hip/hip_bf16.h>

#define NN 100000      // nodes
#define NE 1600000     // edges
#define HD 128         // hidden dim
#define NG 64          // graphs
#define NC 10          // classes
#define NB 391         // dst buckets: b = dst >> 8 (256 nodes per bucket)
#define BCAP 4608      // per-bucket capacity (mean 4096, sigma 64 -> +8 sigma)
#define CHUNK 6400     // edges per k_bin2 block (NE/CHUNK = 250 exactly)

typedef short bf16x8 __attribute__((ext_vector_type(8)));
typedef float f32x4 __attribute__((ext_vector_type(4)));

__device__ __forceinline__ unsigned pk_bf16(float a, float b) {
  unsigned ua = __float_as_uint(a);
  unsigned ub = __float_as_uint(b);
  unsigned ra = (ua + 0x7fffu + ((ua >> 16) & 1u)) >> 16;  // RNE to bf16
  unsigned rb = (ub + 0x7fffu + ((ub >> 16) & 1u)) >> 16;
  return ra | (rb << 16);
}

#define ACC_U4(v)                                  \
  do {                                             \
    a0 += __uint_as_float((v).x << 16);            \
    a1 += __uint_as_float((v).x & 0xffff0000u);    \
    a2 += __uint_as_float((v).y << 16);            \
    a3 += __uint_as_float((v).y & 0xffff0000u);    \
    a4 += __uint_as_float((v).z << 16);            \
    a5 += __uint_as_float((v).z & 0xffff0000u);    \
    a6 += __uint_as_float((v).w << 16);            \
    a7 += __uint_as_float((v).w & 0xffff0000u);    \
  } while (0)

// ---------- pass 1: LDS multi-split binning ----------
__global__ __launch_bounds__(256) void k_bin2(const int* __restrict__ src, const int* __restrict__ dst,
                                              int* __restrict__ bcnt, unsigned* __restrict__ bkt) {
  __shared__ int cl[NB];
  __shared__ int cb[NB];
  int tid = threadIdx.x;
  int base_e = blockIdx.x * CHUNK;
  for (int i = tid; i < NB; i += 256) cl[i] = 0;
  __syncthreads();
  #pragma unroll 5
  for (int j = 0; j < CHUNK / 256; ++j) {
    int d = dst[base_e + j * 256 + tid];
    atomicAdd(&cl[d >> 8], 1);
  }
  __syncthreads();
  for (int i = tid; i < NB; i += 256) {
    cb[i] = atomicAdd(&bcnt[i], cl[i]);
    cl[i] = 0;
  }
  __syncthreads();
  #pragma unroll 5
  for (int j = 0; j < CHUNK / 256; ++j) {
    int e = base_e + j * 256 + tid;
    int s = src[e];
    int d = dst[e];
    int b = d >> 8;
    int p = atomicAdd(&cl[b], 1);
    int idx = cb[b] + p;
    if (idx < BCAP)
      bkt[(size_t)b * BCAP + idx] = (unsigned)s | ((unsigned)(d & 255) << 24);
  }
}

// ---------- pass 2: per-bucket CSR build entirely in LDS ----------
__global__ __launch_bounds__(256) void k_fill2(const unsigned* __restrict__ bkt,
                                               const int* __restrict__ bcnt,
                                               int* __restrict__ rows, int* __restrict__ rowe,
                                               float* __restrict__ dis, int* __restrict__ csr) {
  __shared__ unsigned eds[BCAP];
  __shared__ int sc[256];
  int b = blockIdx.x;
  int tid = threadIdx.x;
  int n = bcnt[b];
  if (n > BCAP) n = BCAP;
  const unsigned* mb = bkt + (size_t)b * BCAP;
  for (int i = tid; i < n; i += 256) eds[i] = mb[i];
  sc[tid] = 0;
  __syncthreads();
  for (int i = tid; i < n; i += 256) atomicAdd(&sc[eds[i] >> 24], 1);
  __syncthreads();
  int deg = sc[tid];
  for (int off = 1; off < 256; off <<= 1) {
    int v = (tid >= off) ? sc[tid - off] : 0;
    __syncthreads();
    sc[tid] += v;
    __syncthreads();
  }
  int excl = sc[tid] - deg;
  int node = b * 256 + tid;
  int cbase = b * BCAP;
  if (node < NN) {
    rows[node] = cbase + excl;
    rowe[node] = cbase + excl + deg;
    dis[node] = rsqrtf((float)(deg + 1));
  }
  __syncthreads();
  sc[tid] = excl;
  __syncthreads();
  for (int i = tid; i < n; i += 256) {
    unsigned v = eds[i];
    int p = atomicAdd(&sc[v >> 24], 1);
    csr[cbase + p] = (int)(v & 0xFFFFFFu);
  }
}

// ---------- W prep: WT[n][k] bf16-pair packed, from W[k][n] f32 ----------
__global__ __launch_bounds__(256) void k_prepW(const float* __restrict__ W1, const float* __restrict__ W2,
                                               unsigned* __restrict__ WT1, unsigned* __restrict__ WT2) {
  int i = blockIdx.x * 256 + threadIdx.x;
  const float* W = (i < 8192) ? W1 : W2;
  unsigned* WT = (i < 8192) ? WT1 : WT2;
  int j = i & 8191;
  int n = j >> 6, kh = j & 63;
  WT[j] = pk_bf16(W[(2 * kh) * HD + n], W[(2 * kh + 1) * HD + n]);
}

// ---------- MFMA GEMM: Y[node] = dis[node] * (X @ W), bf16x2-packed out ----------
template<bool BF16IN>
__global__ __launch_bounds__(256) void k_gemm_mfma(const void* __restrict__ Xin,
                                                   const unsigned* __restrict__ WT,
                                                   const float* __restrict__ dis,
                                                   unsigned* __restrict__ Y) {
  __shared__ char WL[128 * 256];  // [n][k] bf16, XOR-swizzled
  __shared__ char XL[64 * 256];   // [node][k] bf16, XOR-swizzled
  int t = threadIdx.x;
  int rowBase = blockIdx.x * 64;
  {
    const uint4* Wg = (const uint4*)WT;
    for (int i = t; i < 2048; i += 256) {
      int n = i >> 4, kq = i & 15;
      uint4 v = Wg[i];
      *(uint4*)(WL + ((n * 256 + kq * 16) ^ ((n & 7) << 4))) = v;
    }
  }
  if (BF16IN) {
    const uint4* Xg = (const uint4*)Xin;
    for (int i = t; i < 1024; i += 256) {
      int node = i >> 4, c = i & 15;
      int gn = rowBase + node; if (gn >= NN) gn = 0;
      uint4 v = Xg[(size_t)gn * 16 + c];
      *(uint4*)(XL + ((node * 256 + c * 16) ^ ((node & 7) << 4))) = v;
    }
  } else {
    const float4* Xg = (const float4*)Xin;
    for (int i = t; i < 1024; i += 256) {
      int node = i >> 4, c = i & 15;
      int gn = rowBase + node; if (gn >= NN) gn = 0;
      float4 a = Xg[(size_t)gn * 32 + c * 2];
      float4 b = Xg[(size_t)gn * 32 + c * 2 + 1];
      uint4 v;
      v.x = pk_bf16(a.x, a.y); v.y = pk_bf16(a.z, a.w);
      v.z = pk_bf16(b.x, b.y); v.w = pk_bf16(b.z, b.w);
      *(uint4*)(XL + ((node * 256 + c * 16) ^ ((node & 7) << 4))) = v;
    }
  }
  __syncthreads();
  int w = t >> 6, l = t & 63;
  int lr = l & 15, lh = l >> 4;
  int xnode = w * 16 + lr;
  bf16x8 bfrag[4];
  #pragma unroll
  for (int ks = 0; ks < 4; ++ks)
    bfrag[ks] = *(bf16x8*)(XL + ((xnode * 256 + (ks * 32 + lh * 8) * 2) ^ ((xnode & 7) << 4)));
  f32x4 acc[8];
  #pragma unroll
  for (int ct = 0; ct < 8; ++ct) acc[ct] = (f32x4){0.f, 0.f, 0.f, 0.f};
  #pragma unroll
  for (int ct = 0; ct < 8; ++ct) {
    int n = ct * 16 + lr;
    #pragma unroll
    for (int ks = 0; ks < 4; ++ks) {
      bf16x8 af = *(bf16x8*)(WL + ((n * 256 + (ks * 32 + lh * 8) * 2) ^ ((n & 7) << 4)));
      acc[ct] = __builtin_amdgcn_mfma_f32_16x16x32_bf16(af, bfrag[ks], acc[ct], 0, 0, 0);
    }
  }
  int gnode = rowBase + w * 16 + lr;
  if (gnode < NN) {
    float ds = dis[gnode];
    uint2* Yp = (uint2*)(Y + (size_t)gnode * 64);
    #pragma unroll
    for (int ct = 0; ct < 8; ++ct) {
      uint2 o;
      o.x = pk_bf16(acc[ct].x * ds, acc[ct].y * ds);
      o.y = pk_bf16(acc[ct].z * ds, acc[ct].w * ds);
      Yp[ct * 4 + lh] = o;
    }
  }
}

// ---------- pull aggregation: one wave per node, uint4-wide gather ----------
// 16 lanes cover a row (lane li owns features [8li,8li+8)); subs (lane>>4) split edges.
// MODE 0: write packed bf16x2 row; MODE 1: write f32 row (for k_pool)
template<int MODE>
__global__ __launch_bounds__(256) void k_agg(const unsigned* __restrict__ Y, const int* __restrict__ rows,
                                             const int* __restrict__ rowe, const int* __restrict__ csr,
                                             const float* __restrict__ dis,
                                             const float* __restrict__ bias,
                                             void* __restrict__ OUT) {
  int node = __builtin_amdgcn_readfirstlane((blockIdx.x << 2) + (threadIdx.x >> 6));
  int lane = threadIdx.x & 63;
  int sub = lane >> 4, li = lane & 15;
  const uint4* Yv = (const uint4*)Y;   // [node][16] uint4
  float a0 = 0.f, a1 = 0.f, a2 = 0.f, a3 = 0.f, a4 = 0.f, a5 = 0.f, a6 = 0.f, a7 = 0.f;
  if (sub == 0) {
    uint4 sv = Yv[(size_t)node * 16 + li];   // self-loop (di*Ys[node])
    ACC_U4(sv);
  }
  int i = rows[node] + sub, end = rowe[node];
  for (; i + 4 < end; i += 8) {
    int s0 = csr[i], s1 = csr[i + 4];
    uint4 v0 = Yv[(size_t)s0 * 16 + li];
    uint4 v1 = Yv[(size_t)s1 * 16 + li];
    ACC_U4(v0);
    ACC_U4(v1);
  }
  if (i < end) {
    uint4 v = Yv[(size_t)csr[i] * 16 + li];
    ACC_U4(v);
  }
  // butterfly reduce across the 4 subs
  a0 += __shfl_xor(a0, 16, 64); a0 += __shfl_xor(a0, 32, 64);
  a1 += __shfl_xor(a1, 16, 64); a1 += __shfl_xor(a1, 32, 64);
  a2 += __shfl_xor(a2, 16, 64); a2 += __shfl_xor(a2, 32, 64);
  a3 += __shfl_xor(a3, 16, 64); a3 += __shfl_xor(a3, 32, 64);
  a4 += __shfl_xor(a4, 16, 64); a4 += __shfl_xor(a4, 32, 64);
  a5 += __shfl_xor(a5, 16, 64); a5 += __shfl_xor(a5, 32, 64);
  a6 += __shfl_xor(a6, 16, 64); a6 += __shfl_xor(a6, 32, 64);
  a7 += __shfl_xor(a7, 16, 64); a7 += __shfl_xor(a7, 32, 64);
  if (sub != 0) return;
  float di = dis[node];
  const float4* bp = (const float4*)bias;
  float4 b0 = bp[li * 2], b1 = bp[li * 2 + 1];
  float o0 = fmaxf(fmaf(di, a0, b0.x), 0.f);
  float o1 = fmaxf(fmaf(di, a1, b0.y), 0.f);
  float o2 = fmaxf(fmaf(di, a2, b0.z), 0.f);
  float o3 = fmaxf(fmaf(di, a3, b0.w), 0.f);
  float o4 = fmaxf(fmaf(di, a4, b1.x), 0.f);
  float o5 = fmaxf(fmaf(di, a5, b1.y), 0.f);
  float o6 = fmaxf(fmaf(di, a6, b1.z), 0.f);
  float o7 = fmaxf(fmaf(di, a7, b1.w), 0.f);
  if (MODE == 0) {
    uint4 pv;
    pv.x = pk_bf16(o0, o1);
    pv.y = pk_bf16(o2, o3);
    pv.z = pk_bf16(o4, o5);
    pv.w = pk_bf16(o6, o7);
    ((uint4*)OUT)[(size_t)node * 16 + li] = pv;
  } else {
    float4* Op = (float4*)OUT + (size_t)node * 32 + li * 2;
    Op[0] = make_float4(o0, o1, o2, o3);
    Op[1] = make_float4(o4, o5, o6, o7);
  }
}

// ---------- pooling ----------
__global__ __launch_bounds__(256) void k_bounds(const int* __restrict__ bat, int* __restrict__ sg,
                                                int* __restrict__ eg) {
  int i = blockIdx.x * 256 + threadIdx.x;
  if (i < NN) {
    int g = bat[i];
    if (i == 0 || bat[i - 1] != g) sg[g] = i;
    if (i == NN - 1 || bat[i + 1] != g) eg[g] = i + 1;
  }
}

__global__ __launch_bounds__(128) void k_pool(const float* __restrict__ Hf, const int* __restrict__ sg,
                                              const int* __restrict__ eg, float* __restrict__ sums) {
  int g = blockIdx.x >> 5;
  int sl = blockIdx.x & 31;
  int f = threadIdx.x;
  int s = sg[g], e = eg[g];
  float acc = 0.f;
  for (int n = s + sl; n < e; n += 32) acc += Hf[(size_t)n * HD + f];
  atomicAdd(&sums[g * HD + f], acc);
}

__global__ __launch_bounds__(640) void k_fc(const float* __restrict__ sums, const int* __restrict__ sg,
                                            const int* __restrict__ eg, const float* __restrict__ Wfc,
                                            const float* __restrict__ bfc, float* __restrict__ out) {
  int t = threadIdx.x;
  if (t >= NG * NC) return;
  int g = t / NC, c = t - g * NC;
  int cntn = eg[g] - sg[g];
  float inv = 1.0f / fmaxf((float)cntn, 1.0f);
  float acc = 0.f;
  for (int f = 0; f < HD; ++f) acc = fmaf(sums[g * HD + f], Wfc[f * NC + c], acc);
  out[t] = acc * inv + bfc[c];
}

extern "C" void kernel_launch(void* const* d_in, const int* in_sizes, int n_in,
                              void* d_out, int out_size, void* d_ws, size_t ws_size,
                              hipStream_t stream) {
  const float* x   = (const float*)d_in[0];
  const int*   ei  = (const int*)d_in[1];
  const int*   bat = (const int*)d_in[2];
  const float* W1  = (const float*)d_in[3];
  const float* b1  = (const float*)d_in[4];
  const float* W2  = (const float*)d_in[5];
  const float* b2  = (const float*)d_in[6];
  const float* Wfc = (const float*)d_in[7];
  const float* bfc = (const float*)d_in[8];
  float* out = (float*)d_out;
  const int* esrc = ei;        // edge_index[0]
  const int* edst = ei + NE;   // edge_index[1]

  char* p = (char*)d_ws;
  auto carve = [&](size_t bytes) { char* r = p; p += (bytes + 255) & ~(size_t)255; return r; };
  float* dis  = (float*)carve((size_t)NN * 4);
  int*   rows = (int*)carve((size_t)NN * 4);
  int*   rowe = (int*)carve((size_t)NN * 4);
  int*   bcnt = (int*)carve((size_t)NB * 4);
  int*   sg   = (int*)carve(NG * 4);
  int*   eg   = (int*)carve(NG * 4);
  float* sums = (float*)carve(NG * HD * 4);
  unsigned* WT1 = (unsigned*)carve(8192 * 4);
  unsigned* WT2 = (unsigned*)carve(8192 * 4);
  int*   csr  = (int*)carve((size_t)NB * BCAP * 4);       // 7.2 MB
  unsigned* Y   = (unsigned*)carve((size_t)NN * 64 * 4);  // 25.6 MB; bkt aliases (dead before gemm1)
  float* H2   = (float*)carve((size_t)NN * HD * 4);       // 51.2 MB f32 layer-2 out
  unsigned* H1b = (unsigned*)H2;                          // layer-1 bf16 out aliases H2 (dead after gemm2)
  unsigned* bkt = Y;

  hipMemsetAsync(bcnt, 0, (size_t)NB * 4, stream);
  hipMemsetAsync(sums, 0, NG * HD * 4, stream);
  hipMemsetAsync(sg, 0, NG * 4, stream);
  hipMemsetAsync(eg, 0, NG * 4, stream);

  k_bin2<<<NE / CHUNK, 256, 0, stream>>>(esrc, edst, bcnt, bkt);
  k_fill2<<<NB, 256, 0, stream>>>(bkt, bcnt, rows, rowe, dis, csr);
  k_prepW<<<64, 256, 0, stream>>>(W1, W2, WT1, WT2);
  k_bounds<<<(NN + 255) / 256, 256, 0, stream>>>(bat, sg, eg);

  int gblocks = (NN + 63) / 64;
  k_gemm_mfma<false><<<gblocks, 256, 0, stream>>>(x, WT1, dis, Y);
  k_agg<0><<<NN / 4, 256, 0, stream>>>(Y, rows, rowe, csr, dis, b1, H1b);
  k_gemm_mfma<true><<<gblocks, 256, 0, stream>>>(H1b, WT2, dis, Y);
  k_agg<1><<<NN / 4, 256, 0, stream>>>(Y, rows, rowe, csr, dis, b2, H2);

  k_pool<<<NG * 32, 128, 0, stream>>>(H2, sg, eg, sums);
  k_fc<<<1, 640, 0, stream>>>(sums, sg, eg, Wfc, bfc, out);
}

// Round 14
// 250.955 us; speedup vs baseline: 5.5154x; 1.0543x over previous
//
#include <hip/hip_runtime.h>
#include <hip/hip_bf16.h>

#define NN 100000      // nodes
#define NE 1600000     // edges
#define HD 128         // hidden dim
#define NG 64          // graphs
#define NC 10          // classes
#define NB 391         // dst buckets: b = dst >> 8 (256 nodes per bucket)
#define BCAP 4608      // per-bucket capacity (mean 4096, sigma 64 -> +8 sigma)
#define CHUNK 6400     // edges per k_bin2 block (NE/CHUNK = 250 exactly)

typedef short bf16x8 __attribute__((ext_vector_type(8)));
typedef float f32x4 __attribute__((ext_vector_type(4)));

__device__ __forceinline__ unsigned pk_bf16(float a, float b) {
  unsigned ua = __float_as_uint(a);
  unsigned ub = __float_as_uint(b);
  unsigned ra = (ua + 0x7fffu + ((ua >> 16) & 1u)) >> 16;  // RNE to bf16
  unsigned rb = (ub + 0x7fffu + ((ub >> 16) & 1u)) >> 16;
  return ra | (rb << 16);
}

#define ACC_U4(v)                                  \
  do {                                             \
    a0 += __uint_as_float((v).x << 16);            \
    a1 += __uint_as_float((v).x & 0xffff0000u);    \
    a2 += __uint_as_float((v).y << 16);            \
    a3 += __uint_as_float((v).y & 0xffff0000u);    \
    a4 += __uint_as_float((v).z << 16);            \
    a5 += __uint_as_float((v).z & 0xffff0000u);    \
    a6 += __uint_as_float((v).w << 16);            \
    a7 += __uint_as_float((v).w & 0xffff0000u);    \
  } while (0)

// ---------- pass 1: LDS multi-split binning ----------
__global__ __launch_bounds__(256) void k_bin2(const int* __restrict__ src, const int* __restrict__ dst,
                                              int* __restrict__ bcnt, unsigned* __restrict__ bkt) {
  __shared__ int cl[NB];
  __shared__ int cb[NB];
  int tid = threadIdx.x;
  int base_e = blockIdx.x * CHUNK;
  for (int i = tid; i < NB; i += 256) cl[i] = 0;
  __syncthreads();
  #pragma unroll 5
  for (int j = 0; j < CHUNK / 256; ++j) {
    int d = dst[base_e + j * 256 + tid];
    atomicAdd(&cl[d >> 8], 1);
  }
  __syncthreads();
  for (int i = tid; i < NB; i += 256) {
    cb[i] = atomicAdd(&bcnt[i], cl[i]);
    cl[i] = 0;
  }
  __syncthreads();
  #pragma unroll 5
  for (int j = 0; j < CHUNK / 256; ++j) {
    int e = base_e + j * 256 + tid;
    int s = src[e];
    int d = dst[e];
    int b = d >> 8;
    int p = atomicAdd(&cl[b], 1);
    int idx = cb[b] + p;
    if (idx < BCAP)
      bkt[(size_t)b * BCAP + idx] = (unsigned)s | ((unsigned)(d & 255) << 24);
  }
}

// ---------- pass 2: per-bucket CSR build entirely in LDS ----------
__global__ __launch_bounds__(256) void k_fill2(const unsigned* __restrict__ bkt,
                                               const int* __restrict__ bcnt,
                                               int* __restrict__ rows, int* __restrict__ rowe,
                                               float* __restrict__ dis, int* __restrict__ csr) {
  __shared__ unsigned eds[BCAP];
  __shared__ int sc[256];
  int b = blockIdx.x;
  int tid = threadIdx.x;
  int n = bcnt[b];
  if (n > BCAP) n = BCAP;
  const unsigned* mb = bkt + (size_t)b * BCAP;
  for (int i = tid; i < n; i += 256) eds[i] = mb[i];
  sc[tid] = 0;
  __syncthreads();
  for (int i = tid; i < n; i += 256) atomicAdd(&sc[eds[i] >> 24], 1);
  __syncthreads();
  int deg = sc[tid];
  for (int off = 1; off < 256; off <<= 1) {
    int v = (tid >= off) ? sc[tid - off] : 0;
    __syncthreads();
    sc[tid] += v;
    __syncthreads();
  }
  int excl = sc[tid] - deg;
  int node = b * 256 + tid;
  int cbase = b * BCAP;
  if (node < NN) {
    rows[node] = cbase + excl;
    rowe[node] = cbase + excl + deg;
    dis[node] = rsqrtf((float)(deg + 1));
  }
  __syncthreads();
  sc[tid] = excl;
  __syncthreads();
  for (int i = tid; i < n; i += 256) {
    unsigned v = eds[i];
    int p = atomicAdd(&sc[v >> 24], 1);
    csr[cbase + p] = (int)(v & 0xFFFFFFu);
  }
}

// ---------- fused small-kernel pass: prepW + graph bounds + zero sums ----------
__global__ __launch_bounds__(256) void k_misc(const float* __restrict__ W1, const float* __restrict__ W2,
                                              unsigned* __restrict__ WT1, unsigned* __restrict__ WT2,
                                              const int* __restrict__ bat, int* __restrict__ sg,
                                              int* __restrict__ eg, float* __restrict__ sums) {
  int bid = blockIdx.x;
  int tid = threadIdx.x;
  if (bid < 64) {
    int i = bid * 256 + tid;
    const float* W = (i < 8192) ? W1 : W2;
    unsigned* WT = (i < 8192) ? WT1 : WT2;
    int j = i & 8191;
    int n = j >> 6, kh = j & 63;
    WT[j] = pk_bf16(W[(2 * kh) * HD + n], W[(2 * kh + 1) * HD + n]);
    if (i < NG * HD) sums[i] = 0.f;
  } else {
    int i = (bid - 64) * 256 + tid;
    if (i < NN) {
      int g = bat[i];
      if (i == 0 || bat[i - 1] != g) sg[g] = i;
      if (i == NN - 1 || bat[i + 1] != g) eg[g] = i + 1;
    }
  }
}

// ---------- MFMA GEMM: Y[node] = dis[node] * (X @ W), bf16x2-packed out ----------
template<bool BF16IN>
__global__ __launch_bounds__(256) void k_gemm_mfma(const void* __restrict__ Xin,
                                                   const unsigned* __restrict__ WT,
                                                   const float* __restrict__ dis,
                                                   unsigned* __restrict__ Y) {
  __shared__ char WL[128 * 256];  // [n][k] bf16, XOR-swizzled
  __shared__ char XL[64 * 256];   // [node][k] bf16, XOR-swizzled
  int t = threadIdx.x;
  int rowBase = blockIdx.x * 64;
  {
    const uint4* Wg = (const uint4*)WT;
    for (int i = t; i < 2048; i += 256) {
      int n = i >> 4, kq = i & 15;
      uint4 v = Wg[i];
      *(uint4*)(WL + ((n * 256 + kq * 16) ^ ((n & 7) << 4))) = v;
    }
  }
  if (BF16IN) {
    const uint4* Xg = (const uint4*)Xin;
    for (int i = t; i < 1024; i += 256) {
      int node = i >> 4, c = i & 15;
      int gn = rowBase + node; if (gn >= NN) gn = 0;
      uint4 v = Xg[(size_t)gn * 16 + c];
      *(uint4*)(XL + ((node * 256 + c * 16) ^ ((node & 7) << 4))) = v;
    }
  } else {
    const float4* Xg = (const float4*)Xin;
    for (int i = t; i < 1024; i += 256) {
      int node = i >> 4, c = i & 15;
      int gn = rowBase + node; if (gn >= NN) gn = 0;
      float4 a = Xg[(size_t)gn * 32 + c * 2];
      float4 b = Xg[(size_t)gn * 32 + c * 2 + 1];
      uint4 v;
      v.x = pk_bf16(a.x, a.y); v.y = pk_bf16(a.z, a.w);
      v.z = pk_bf16(b.x, b.y); v.w = pk_bf16(b.z, b.w);
      *(uint4*)(XL + ((node * 256 + c * 16) ^ ((node & 7) << 4))) = v;
    }
  }
  __syncthreads();
  int w = t >> 6, l = t & 63;
  int lr = l & 15, lh = l >> 4;
  int xnode = w * 16 + lr;
  bf16x8 bfrag[4];
  #pragma unroll
  for (int ks = 0; ks < 4; ++ks)
    bfrag[ks] = *(bf16x8*)(XL + ((xnode * 256 + (ks * 32 + lh * 8) * 2) ^ ((xnode & 7) << 4)));
  f32x4 acc[8];
  #pragma unroll
  for (int ct = 0; ct < 8; ++ct) acc[ct] = (f32x4){0.f, 0.f, 0.f, 0.f};
  #pragma unroll
  for (int ct = 0; ct < 8; ++ct) {
    int n = ct * 16 + lr;
    #pragma unroll
    for (int ks = 0; ks < 4; ++ks) {
      bf16x8 af = *(bf16x8*)(WL + ((n * 256 + (ks * 32 + lh * 8) * 2) ^ ((n & 7) << 4)));
      acc[ct] = __builtin_amdgcn_mfma_f32_16x16x32_bf16(af, bfrag[ks], acc[ct], 0, 0, 0);
    }
  }
  int gnode = rowBase + w * 16 + lr;
  if (gnode < NN) {
    float ds = dis[gnode];
    uint2* Yp = (uint2*)(Y + (size_t)gnode * 64);
    #pragma unroll
    for (int ct = 0; ct < 8; ++ct) {
      uint2 o;
      o.x = pk_bf16(acc[ct].x * ds, acc[ct].y * ds);
      o.y = pk_bf16(acc[ct].z * ds, acc[ct].w * ds);
      Yp[ct * 4 + lh] = o;
    }
  }
}

// ---------- pull aggregation: one wave per node, uint4 gather, 4-deep MLP ----------
// 16 lanes cover a row (lane li owns features [8li,8li+8)); sub (lane>>4) owns a
// CONTIGUOUS quarter of the edge list -> typical sub runs one 4-wide iteration
// with 4 independent 256B row-loads in flight. Output: packed bf16x2 row.
__global__ __launch_bounds__(256) void k_agg(const unsigned* __restrict__ Y, const int* __restrict__ rows,
                                             const int* __restrict__ rowe, const int* __restrict__ csr,
                                             const float* __restrict__ dis,
                                             const float* __restrict__ bias,
                                             unsigned* __restrict__ OUT) {
  int node = __builtin_amdgcn_readfirstlane((blockIdx.x << 2) + (threadIdx.x >> 6));
  int lane = threadIdx.x & 63;
  int sub = lane >> 4, li = lane & 15;
  const uint4* Yv = (const uint4*)Y;   // [node][16] uint4
  float a0 = 0.f, a1 = 0.f, a2 = 0.f, a3 = 0.f, a4 = 0.f, a5 = 0.f, a6 = 0.f, a7 = 0.f;
  int start = rows[node], len = rowe[node] - start;
  if (sub == 0) {
    uint4 sv = Yv[(size_t)node * 16 + li];   // self-loop (di*Ys[node])
    ACC_U4(sv);
  }
  int i = start + ((len * sub) >> 2);
  int q1 = start + ((len * (sub + 1)) >> 2);
  for (; i + 4 <= q1; i += 4) {
    int s0 = csr[i], s1 = csr[i + 1], s2 = csr[i + 2], s3 = csr[i + 3];
    uint4 v0 = Yv[(size_t)s0 * 16 + li];
    uint4 v1 = Yv[(size_t)s1 * 16 + li];
    uint4 v2 = Yv[(size_t)s2 * 16 + li];
    uint4 v3 = Yv[(size_t)s3 * 16 + li];
    ACC_U4(v0);
    ACC_U4(v1);
    ACC_U4(v2);
    ACC_U4(v3);
  }
  for (; i < q1; ++i) {
    uint4 v = Yv[(size_t)csr[i] * 16 + li];
    ACC_U4(v);
  }
  // butterfly reduce across the 4 subs
  a0 += __shfl_xor(a0, 16, 64); a0 += __shfl_xor(a0, 32, 64);
  a1 += __shfl_xor(a1, 16, 64); a1 += __shfl_xor(a1, 32, 64);
  a2 += __shfl_xor(a2, 16, 64); a2 += __shfl_xor(a2, 32, 64);
  a3 += __shfl_xor(a3, 16, 64); a3 += __shfl_xor(a3, 32, 64);
  a4 += __shfl_xor(a4, 16, 64); a4 += __shfl_xor(a4, 32, 64);
  a5 += __shfl_xor(a5, 16, 64); a5 += __shfl_xor(a5, 32, 64);
  a6 += __shfl_xor(a6, 16, 64); a6 += __shfl_xor(a6, 32, 64);
  a7 += __shfl_xor(a7, 16, 64); a7 += __shfl_xor(a7, 32, 64);
  if (sub != 0) return;
  float di = dis[node];
  const float4* bp = (const float4*)bias;
  float4 b0 = bp[li * 2], b1 = bp[li * 2 + 1];
  float o0 = fmaxf(fmaf(di, a0, b0.x), 0.f);
  float o1 = fmaxf(fmaf(di, a1, b0.y), 0.f);
  float o2 = fmaxf(fmaf(di, a2, b0.z), 0.f);
  float o3 = fmaxf(fmaf(di, a3, b0.w), 0.f);
  float o4 = fmaxf(fmaf(di, a4, b1.x), 0.f);
  float o5 = fmaxf(fmaf(di, a5, b1.y), 0.f);
  float o6 = fmaxf(fmaf(di, a6, b1.z), 0.f);
  float o7 = fmaxf(fmaf(di, a7, b1.w), 0.f);
  uint4 pv;
  pv.x = pk_bf16(o0, o1);
  pv.y = pk_bf16(o2, o3);
  pv.z = pk_bf16(o4, o5);
  pv.w = pk_bf16(o6, o7);
  ((uint4*)OUT)[(size_t)node * 16 + li] = pv;
}

// ---------- pooling over bf16 H rows ----------
// grid NG*8; block 256 = 4 node-slots x 64 pair-lanes (u32 = 2 bf16 features)
__global__ __launch_bounds__(256) void k_pool(const unsigned* __restrict__ Hb, const int* __restrict__ sg,
                                              const int* __restrict__ eg, float* __restrict__ sums) {
  int g = blockIdx.x >> 3;
  int sl = blockIdx.x & 7;
  int slot = threadIdx.x >> 6;
  int pl = threadIdx.x & 63;
  int s = sg[g], e = eg[g];
  float f0 = 0.f, f1 = 0.f;
  for (int n = s + sl * 4 + slot; n < e; n += 32) {
    unsigned v = Hb[(size_t)n * 64 + pl];
    f0 += __uint_as_float(v << 16);
    f1 += __uint_as_float(v & 0xffff0000u);
  }
  atomicAdd(&sums[g * HD + 2 * pl], f0);
  atomicAdd(&sums[g * HD + 2 * pl + 1], f1);
}

__global__ __launch_bounds__(640) void k_fc(const float* __restrict__ sums, const int* __restrict__ sg,
                                            const int* __restrict__ eg, const float* __restrict__ Wfc,
                                            const float* __restrict__ bfc, float* __restrict__ out) {
  int t = threadIdx.x;
  if (t >= NG * NC) return;
  int g = t / NC, c = t - g * NC;
  int cntn = eg[g] - sg[g];
  float inv = 1.0f / fmaxf((float)cntn, 1.0f);
  float acc = 0.f;
  for (int f = 0; f < HD; ++f) acc = fmaf(sums[g * HD + f], Wfc[f * NC + c], acc);
  out[t] = acc * inv + bfc[c];
}

extern "C" void kernel_launch(void* const* d_in, const int* in_sizes, int n_in,
                              void* d_out, int out_size, void* d_ws, size_t ws_size,
                              hipStream_t stream) {
  const float* x   = (const float*)d_in[0];
  const int*   ei  = (const int*)d_in[1];
  const int*   bat = (const int*)d_in[2];
  const float* W1  = (const float*)d_in[3];
  const float* b1  = (const float*)d_in[4];
  const float* W2  = (const float*)d_in[5];
  const float* b2  = (const float*)d_in[6];
  const float* Wfc = (const float*)d_in[7];
  const float* bfc = (const float*)d_in[8];
  float* out = (float*)d_out;
  const int* esrc = ei;        // edge_index[0]
  const int* edst = ei + NE;   // edge_index[1]

  char* p = (char*)d_ws;
  auto carve = [&](size_t bytes) { char* r = p; p += (bytes + 255) & ~(size_t)255; return r; };
  float* dis  = (float*)carve((size_t)NN * 4);
  int*   rows = (int*)carve((size_t)NN * 4);
  int*   rowe = (int*)carve((size_t)NN * 4);
  int*   bcnt = (int*)carve((size_t)NB * 4);
  int*   sg   = (int*)carve(NG * 4);
  int*   eg   = (int*)carve(NG * 4);
  float* sums = (float*)carve(NG * HD * 4);
  unsigned* WT1 = (unsigned*)carve(8192 * 4);
  unsigned* WT2 = (unsigned*)carve(8192 * 4);
  int*   csr  = (int*)carve((size_t)NB * BCAP * 4);       // 7.2 MB
  unsigned* Y   = (unsigned*)carve((size_t)NN * 64 * 4);  // 25.6 MB; bkt aliases (dead before gemm1)
  unsigned* H1b = (unsigned*)carve((size_t)NN * 64 * 4);  // 25.6 MB; H2b aliases (H1b dead after gemm2)
  unsigned* bkt = Y;
  unsigned* H2b = H1b;

  hipMemsetAsync(bcnt, 0, (size_t)NB * 4, stream);

  k_bin2<<<NE / CHUNK, 256, 0, stream>>>(esrc, edst, bcnt, bkt);
  k_fill2<<<NB, 256, 0, stream>>>(bkt, bcnt, rows, rowe, dis, csr);
  k_misc<<<64 + (NN + 255) / 256, 256, 0, stream>>>(W1, W2, WT1, WT2, bat, sg, eg, sums);

  int gblocks = (NN + 63) / 64;
  k_gemm_mfma<false><<<gblocks, 256, 0, stream>>>(x, WT1, dis, Y);
  k_agg<<<NN / 4, 256, 0, stream>>>(Y, rows, rowe, csr, dis, b1, H1b);
  k_gemm_mfma<true><<<gblocks, 256, 0, stream>>>(H1b, WT2, dis, Y);
  k_agg<<<NN / 4, 256, 0, stream>>>(Y, rows, rowe, csr, dis, b2, H2b);

  k_pool<<<NG * 8, 256, 0, stream>>>(H2b, sg, eg, sums);
  k_fc<<<1, 640, 0, stream>>>(sums, sg, eg, Wfc, bfc, out);
}